// Round 1
// baseline (2306.196 us; speedup 1.0000x reference)
//
#include <hip/hip_runtime.h>
#include <hip/hip_bf16.h>

#define N_NODES 50000
#define N_EDGES 800000
#define FEAT 128
#define HID 64
#define TYPE_NUM 10

// ---------------------------------------------------------------------------
// Fused dual GEMM: Yrel = H @ Wrel, Yroot = H @ Wroot.  H is [N_NODES, IN],
// W's are [IN, 64] row-major. One block = 4 rows x 64 cols, 256 threads.
// ---------------------------------------------------------------------------
template <int IN>
__global__ __launch_bounds__(256) void gemm_dual(const float* __restrict__ H,
                                                 const float* __restrict__ Wrel,
                                                 const float* __restrict__ Wroot,
                                                 float* __restrict__ Yrel,
                                                 float* __restrict__ Yroot) {
    __shared__ float sWrel[IN * 64];
    __shared__ float sWroot[IN * 64];
    __shared__ float sH[4][IN];

    const int tid = threadIdx.x;
    for (int i = tid; i < IN * 64; i += 256) {
        sWrel[i]  = Wrel[i];
        sWroot[i] = Wroot[i];
    }
    const int row0 = blockIdx.x * 4;
    for (int i = tid; i < 4 * IN; i += 256) {
        const int r = i / IN, c = i % IN;
        const int gr = row0 + r;
        sH[r][c] = (gr < N_NODES) ? H[(long long)gr * IN + c] : 0.f;
    }
    __syncthreads();

    const int r   = tid >> 6;   // 0..3  (wave-uniform)
    const int col = tid & 63;   // 0..63
    const int grow = row0 + r;
    if (grow >= N_NODES) return;

    float accR = 0.f, accT = 0.f;
#pragma unroll
    for (int k = 0; k < IN; ++k) {
        const float h = sH[r][k];              // LDS broadcast
        accR += h * sWrel[k * 64 + col];       // 2-way bank alias = free
        accT += h * sWroot[k * 64 + col];
    }
    Yrel[(long long)grow * 64 + col]  = accR;
    Yroot[(long long)grow * 64 + col] = accT;
}

// ---------------------------------------------------------------------------
// Edge scatter: Agg[dst[e]] += Y[src[e]]  (64 f32 per edge).
// Thread = (edge, 4-feature chunk): float4 gather + 4 f32 HW atomics.
// ---------------------------------------------------------------------------
__global__ __launch_bounds__(256) void edge_scatter(const int* __restrict__ src,
                                                    const int* __restrict__ dst,
                                                    const float* __restrict__ Y,
                                                    float* __restrict__ Agg) {
    const long long tid = (long long)blockIdx.x * blockDim.x + threadIdx.x;
    if (tid >= (long long)N_EDGES * 16) return;
    const int e = (int)(tid >> 4);
    const int c = (int)(tid & 15) << 2;
    const int s = src[e];
    const int d = dst[e];
    const float4 v = *reinterpret_cast<const float4*>(Y + (long long)s * 64 + c);
    float* p = Agg + (long long)d * 64 + c;
    unsafeAtomicAdd(p + 0, v.x);
    unsafeAtomicAdd(p + 1, v.y);
    unsafeAtomicAdd(p + 2, v.z);
    unsafeAtomicAdd(p + 3, v.w);
}

// ---------------------------------------------------------------------------
// h = relu(A + B), elementwise float4 over N_NODES*64 floats.
// ---------------------------------------------------------------------------
__global__ __launch_bounds__(256) void relu_combine(const float4* __restrict__ A,
                                                    const float4* __restrict__ B,
                                                    float4* __restrict__ O) {
    const int i = blockIdx.x * 256 + threadIdx.x;
    if (i >= N_NODES * HID / 4) return;
    const float4 a = A[i];
    const float4 b = B[i];
    float4 o;
    o.x = fmaxf(a.x + b.x, 0.f);
    o.y = fmaxf(a.y + b.y, 0.f);
    o.z = fmaxf(a.z + b.z, 0.f);
    o.w = fmaxf(a.w + b.w, 0.f);
    O[i] = o;
}

// ---------------------------------------------------------------------------
// Pool graph 0: sums[f] += relu(Agg[n][f] + Yroot[n][f]) for batch[n]==0,
// plus node count. pool = 64 sums + 1 count.
// ---------------------------------------------------------------------------
__global__ __launch_bounds__(256) void pool0(const float* __restrict__ Agg,
                                             const float* __restrict__ Yroot,
                                             const int* __restrict__ batch,
                                             float* __restrict__ pool) {
    const int node = blockIdx.x * 4 + (threadIdx.x >> 6);
    const int f    = threadIdx.x & 63;
    if (node >= N_NODES) return;
    if (batch[node] != 0) return;
    float h = Agg[(long long)node * 64 + f] + Yroot[(long long)node * 64 + f];
    h = fmaxf(h, 0.f);
    unsafeAtomicAdd(&pool[f], h);
    if (f == 0) unsafeAtomicAdd(&pool[64], 1.0f);
}

// ---------------------------------------------------------------------------
// Head: means = sums/count; logits = means @ Wfc + bfc; softmax; out[0..9].
// ---------------------------------------------------------------------------
__global__ void head(const float* __restrict__ pool,
                     const float* __restrict__ Wfc,
                     const float* __restrict__ bfc,
                     float* __restrict__ out) {
    __shared__ float logits[TYPE_NUM];
    const int t = threadIdx.x;
    const float inv = 1.0f / fmaxf(pool[64], 1.0f);
    if (t < TYPE_NUM) {
        float acc = bfc[t];
        for (int f = 0; f < HID; ++f)
            acc += pool[f] * inv * Wfc[f * TYPE_NUM + t];
        logits[t] = acc;
    }
    __syncthreads();
    if (t == 0) {
        float m = -1e30f;
        for (int i = 0; i < TYPE_NUM; ++i) m = fmaxf(m, logits[i]);
        float ssum = 0.f;
        float e[TYPE_NUM];
        for (int i = 0; i < TYPE_NUM; ++i) { e[i] = __expf(logits[i] - m); ssum += e[i]; }
        for (int i = 0; i < TYPE_NUM; ++i) out[i] = e[i] / ssum;
    }
}

extern "C" void kernel_launch(void* const* d_in, const int* in_sizes, int n_in,
                              void* d_out, int out_size, void* d_ws, size_t ws_size,
                              hipStream_t stream) {
    const float* x      = (const float*)d_in[0];
    const int*   eidx   = (const int*)d_in[1];
    const int*   batch  = (const int*)d_in[2];
    const float* Wrel1  = (const float*)d_in[3];
    const float* Wroot1 = (const float*)d_in[4];
    const float* Wrel2  = (const float*)d_in[5];
    const float* Wroot2 = (const float*)d_in[6];
    const float* Wrel3  = (const float*)d_in[7];
    const float* Wroot3 = (const float*)d_in[8];
    const float* Wfc    = (const float*)d_in[9];
    const float* bfc    = (const float*)d_in[10];
    float* out = (float*)d_out;

    const int* src = eidx;             // edge_index[0]
    const int* dst = eidx + N_EDGES;   // edge_index[1]

    const long long NN = (long long)N_NODES * HID;        // 3.2M floats
    const size_t NB = NN * sizeof(float);                 // 12.8 MB
    float* B0   = (float*)d_ws;
    float* B1   = B0 + NN;
    float* B2   = B1 + NN;
    float* pool = B2 + NN;                                // 65 floats

    const int gGemm    = (N_NODES + 3) / 4;               // 12500
    const int gScatter = (int)(((long long)N_EDGES * 16 + 255) / 256);  // 50000
    const int gComb    = (int)((NN / 4 + 255) / 256);     // 3125

    // ---- Layer 1 (IN=128): yrel->B0, yroot->B1, agg->B2, h1->B0
    gemm_dual<FEAT><<<gGemm, 256, 0, stream>>>(x, Wrel1, Wroot1, B0, B1);
    hipMemsetAsync(B2, 0, NB, stream);
    edge_scatter<<<gScatter, 256, 0, stream>>>(src, dst, B0, B2);
    relu_combine<<<gComb, 256, 0, stream>>>((const float4*)B2, (const float4*)B1, (float4*)B0);

    // ---- Layer 2 (IN=64): h1 in B0 -> yrel B1, yroot B2; agg->B0(free); h2->B1
    gemm_dual<HID><<<gGemm, 256, 0, stream>>>(B0, Wrel2, Wroot2, B1, B2);
    hipMemsetAsync(B0, 0, NB, stream);
    edge_scatter<<<gScatter, 256, 0, stream>>>(src, dst, B1, B0);
    relu_combine<<<gComb, 256, 0, stream>>>((const float4*)B0, (const float4*)B2, (float4*)B1);

    // ---- Layer 3 (IN=64): h2 in B1 -> yrel B2, yroot B0; agg->B1; pool fused relu
    gemm_dual<HID><<<gGemm, 256, 0, stream>>>(B1, Wrel3, Wroot3, B2, B0);
    hipMemsetAsync(B1, 0, NB, stream);
    edge_scatter<<<gScatter, 256, 0, stream>>>(src, dst, B2, B1);

    // ---- Pool graph 0 + head
    hipMemsetAsync(pool, 0, 68 * sizeof(float), stream);
    pool0<<<gGemm, 256, 0, stream>>>(B1, B0, batch, pool);
    head<<<1, 64, 0, stream>>>(pool, Wfc, bfc, out);
}

// Round 2
// 569.981 us; speedup vs baseline: 4.0461x; 4.0461x over previous
//
#include <hip/hip_runtime.h>
#include <hip/hip_bf16.h>

#define N_NODES 50000
#define N_EDGES 800000
#define FEAT 128
#define HID 64
#define TYPE_NUM 10
#define SCAN_T 1024

// ---------------------------------------------------------------------------
// Fused dual GEMM: Yrel = H @ Wrel, Yroot = H @ Wroot.  H is [N_NODES, IN],
// W's are [IN, 64] row-major. One block = 4 rows x 64 cols, 256 threads.
// ---------------------------------------------------------------------------
template <int IN>
__global__ __launch_bounds__(256) void gemm_dual(const float* __restrict__ H,
                                                 const float* __restrict__ Wrel,
                                                 const float* __restrict__ Wroot,
                                                 float* __restrict__ Yrel,
                                                 float* __restrict__ Yroot) {
    __shared__ float sWrel[IN * 64];
    __shared__ float sWroot[IN * 64];
    __shared__ float sH[4][IN];

    const int tid = threadIdx.x;
    for (int i = tid; i < IN * 64; i += 256) {
        sWrel[i]  = Wrel[i];
        sWroot[i] = Wroot[i];
    }
    const int row0 = blockIdx.x * 4;
    for (int i = tid; i < 4 * IN; i += 256) {
        const int r = i / IN, c = i % IN;
        const int gr = row0 + r;
        sH[r][c] = (gr < N_NODES) ? H[(long long)gr * IN + c] : 0.f;
    }
    __syncthreads();

    const int r   = tid >> 6;   // 0..3  (wave-uniform)
    const int col = tid & 63;   // 0..63
    const int grow = row0 + r;
    if (grow >= N_NODES) return;

    float accR = 0.f, accT = 0.f;
#pragma unroll
    for (int k = 0; k < IN; ++k) {
        const float h = sH[r][k];              // LDS broadcast
        accR += h * sWrel[k * 64 + col];       // 2-way bank alias = free
        accT += h * sWroot[k * 64 + col];
    }
    Yrel[(long long)grow * 64 + col]  = accR;
    Yroot[(long long)grow * 64 + col] = accT;
}

// ---------------------------------------------------------------------------
// CSR build step 1: histogram of dst.
// ---------------------------------------------------------------------------
__global__ __launch_bounds__(256) void hist_dst(const int* __restrict__ dst,
                                                int* __restrict__ cnt) {
    const int e = blockIdx.x * 256 + threadIdx.x;
    if (e < N_EDGES) atomicAdd(&cnt[dst[e]], 1);
}

// ---------------------------------------------------------------------------
// CSR build step 2: exclusive scan of cnt[0..N_NODES) -> rowptr, cursor.
// Single block, SCAN_T threads, each owns a contiguous chunk.
// ---------------------------------------------------------------------------
__global__ __launch_bounds__(SCAN_T) void scan_rows(const int* __restrict__ cnt,
                                                    int* __restrict__ rowptr,
                                                    int* __restrict__ cursor) {
    __shared__ int part[SCAN_T];
    const int t = threadIdx.x;
    const int CH = (N_NODES + SCAN_T - 1) / SCAN_T;   // 49
    const int base = t * CH;
    int s = 0;
    for (int i = 0; i < CH; ++i) {
        const int idx = base + i;
        if (idx < N_NODES) s += cnt[idx];
    }
    part[t] = s;
    __syncthreads();
    // Hillis-Steele inclusive scan
    for (int off = 1; off < SCAN_T; off <<= 1) {
        int v = 0;
        if (t >= off) v = part[t - off];
        __syncthreads();
        if (t >= off) part[t] += v;
        __syncthreads();
    }
    int run = (t == 0) ? 0 : part[t - 1];   // exclusive prefix of this chunk
    for (int i = 0; i < CH; ++i) {
        const int idx = base + i;
        if (idx < N_NODES) {
            rowptr[idx] = run;
            cursor[idx] = run;
            run += cnt[idx];
        }
    }
    if (t == 0) rowptr[N_NODES] = N_EDGES;
}

// ---------------------------------------------------------------------------
// CSR build step 3: fill column (src) indices.
// ---------------------------------------------------------------------------
__global__ __launch_bounds__(256) void fill_csr(const int* __restrict__ src,
                                                const int* __restrict__ dst,
                                                int* __restrict__ cursor,
                                                int* __restrict__ col) {
    const int e = blockIdx.x * 256 + threadIdx.x;
    if (e >= N_EDGES) return;
    const int p = atomicAdd(&cursor[dst[e]], 1);
    col[p] = src[e];
}

// ---------------------------------------------------------------------------
// Gather aggregation + fused relu(agg + root). One 64-lane wave per node,
// lane = feature. Per edge: one coalesced 256B row read (L2/L3-resident).
// FUSE_POOL: layer 3 — skip Out write, atomically pool graph-0 rows.
// ---------------------------------------------------------------------------
template <bool FUSE_POOL>
__global__ __launch_bounds__(256) void aggregate(const int* __restrict__ rowptr,
                                                 const int* __restrict__ col,
                                                 const float* __restrict__ Y,
                                                 const float* __restrict__ Yroot,
                                                 const int* __restrict__ batch,
                                                 float* __restrict__ Out,
                                                 float* __restrict__ pool) {
    const int node = blockIdx.x * 4 + (threadIdx.x >> 6);
    const int f    = threadIdx.x & 63;
    if (node >= N_NODES) return;
    const int beg = rowptr[node];
    const int end = rowptr[node + 1];
    float acc = 0.f;
    int j = beg;
    for (; j + 1 < end; j += 2) {          // 2-way ILP on the random gathers
        const int s0 = col[j];
        const int s1 = col[j + 1];
        const float v0 = Y[(long long)s0 * 64 + f];
        const float v1 = Y[(long long)s1 * 64 + f];
        acc += v0;
        acc += v1;
    }
    if (j < end) acc += Y[(long long)col[j] * 64 + f];

    float h = fmaxf(acc + Yroot[(long long)node * 64 + f], 0.f);
    if (FUSE_POOL) {
        if (batch[node] == 0) {
            unsafeAtomicAdd(&pool[f], h);
            if (f == 0) unsafeAtomicAdd(&pool[64], 1.0f);
        }
    } else {
        Out[(long long)node * 64 + f] = h;
    }
}

// ---------------------------------------------------------------------------
// Head: means = sums/count; logits = means @ Wfc + bfc; softmax; out[0..9].
// ---------------------------------------------------------------------------
__global__ void head(const float* __restrict__ pool,
                     const float* __restrict__ Wfc,
                     const float* __restrict__ bfc,
                     float* __restrict__ out) {
    __shared__ float logits[TYPE_NUM];
    const int t = threadIdx.x;
    const float inv = 1.0f / fmaxf(pool[64], 1.0f);
    if (t < TYPE_NUM) {
        float acc = bfc[t];
        for (int f = 0; f < HID; ++f)
            acc += pool[f] * inv * Wfc[f * TYPE_NUM + t];
        logits[t] = acc;
    }
    __syncthreads();
    if (t == 0) {
        float m = -1e30f;
        for (int i = 0; i < TYPE_NUM; ++i) m = fmaxf(m, logits[i]);
        float ssum = 0.f;
        float e[TYPE_NUM];
        for (int i = 0; i < TYPE_NUM; ++i) { e[i] = __expf(logits[i] - m); ssum += e[i]; }
        for (int i = 0; i < TYPE_NUM; ++i) out[i] = e[i] / ssum;
    }
}

extern "C" void kernel_launch(void* const* d_in, const int* in_sizes, int n_in,
                              void* d_out, int out_size, void* d_ws, size_t ws_size,
                              hipStream_t stream) {
    const float* x      = (const float*)d_in[0];
    const int*   eidx   = (const int*)d_in[1];
    const int*   batch  = (const int*)d_in[2];
    const float* Wrel1  = (const float*)d_in[3];
    const float* Wroot1 = (const float*)d_in[4];
    const float* Wrel2  = (const float*)d_in[5];
    const float* Wroot2 = (const float*)d_in[6];
    const float* Wrel3  = (const float*)d_in[7];
    const float* Wroot3 = (const float*)d_in[8];
    const float* Wfc    = (const float*)d_in[9];
    const float* bfc    = (const float*)d_in[10];
    float* out = (float*)d_out;

    const int* src = eidx;             // edge_index[0]
    const int* dst = eidx + N_EDGES;   // edge_index[1]

    const long long NN = (long long)N_NODES * HID;        // 3.2M floats
    float* B0   = (float*)d_ws;
    float* B1   = B0 + NN;
    float* B2   = B1 + NN;
    float* pool = B2 + NN;                                // 68 floats (pad)
    int* rowptr = (int*)(pool + 68);                      // N_NODES+1
    int* cursor = rowptr + (N_NODES + 1);                 // N_NODES
    int* cnt    = cursor + N_NODES;                       // N_NODES
    int* colidx = cnt + N_NODES;                          // N_EDGES

    const int gNode = (N_NODES + 3) / 4;                  // 12500
    const int gEdge = (N_EDGES + 255) / 256;              // 3125

    // ---- Build CSR (by dst) once; reused by all 3 layers.
    hipMemsetAsync(cnt, 0, N_NODES * sizeof(int), stream);
    hipMemsetAsync(pool, 0, 68 * sizeof(float), stream);
    hist_dst<<<gEdge, 256, 0, stream>>>(dst, cnt);
    scan_rows<<<1, SCAN_T, 0, stream>>>(cnt, rowptr, cursor);
    fill_csr<<<gEdge, 256, 0, stream>>>(src, dst, cursor, colidx);

    // ---- Layer 1 (IN=128): x -> Yrel B0, Yroot B1; h1 -> B2
    gemm_dual<FEAT><<<gNode, 256, 0, stream>>>(x, Wrel1, Wroot1, B0, B1);
    aggregate<false><<<gNode, 256, 0, stream>>>(rowptr, colidx, B0, B1, batch, B2, pool);

    // ---- Layer 2 (IN=64): h1 B2 -> Yrel B0, Yroot B1; h2 -> B2
    gemm_dual<HID><<<gNode, 256, 0, stream>>>(B2, Wrel2, Wroot2, B0, B1);
    aggregate<false><<<gNode, 256, 0, stream>>>(rowptr, colidx, B0, B1, batch, B2, pool);

    // ---- Layer 3 (IN=64): h2 B2 -> Yrel B0, Yroot B1; fused pool (no h3 store)
    gemm_dual<HID><<<gNode, 256, 0, stream>>>(B2, Wrel3, Wroot3, B0, B1);
    aggregate<true><<<gNode, 256, 0, stream>>>(rowptr, colidx, B0, B1, batch, nullptr, pool);

    // ---- Head
    head<<<1, 64, 0, stream>>>(pool, Wfc, bfc, out);
}

// Round 3
// 446.119 us; speedup vs baseline: 5.1695x; 1.2776x over previous
//
#include <hip/hip_runtime.h>
#include <hip/hip_bf16.h>

#define N_NODES 50000
#define N_EDGES 800000
#define FEAT 128
#define HID 64
#define TYPE_NUM 10

// ---------------------------------------------------------------------------
// Fused dual GEMM: Yrel = H @ Wrel, Yroot = H @ Wroot.  H is [N_NODES, IN].
// One block = 32 rows (8 groups of 4) x 64 cols, 256 threads. Weights staged
// in LDS ONCE per block (amortized over 32 rows, 8x less staging than 4-row).
// ---------------------------------------------------------------------------
template <int IN, int ROWS>
__global__ __launch_bounds__(256) void gemm_dual(const float* __restrict__ H,
                                                 const float* __restrict__ Wrel,
                                                 const float* __restrict__ Wroot,
                                                 float* __restrict__ Yrel,
                                                 float* __restrict__ Yroot) {
    __shared__ float sWrel[IN * 64];
    __shared__ float sWroot[IN * 64];
    __shared__ float sH[4][IN];

    const int tid = threadIdx.x;
    for (int i = tid; i < IN * 64; i += 256) {
        sWrel[i]  = Wrel[i];
        sWroot[i] = Wroot[i];
    }
    const int row0 = blockIdx.x * ROWS;
    const int r   = tid >> 6;   // 0..3 (wave-uniform)
    const int col = tid & 63;   // 0..63

#pragma unroll 1
    for (int g = 0; g < ROWS / 4; ++g) {
        const int grp0 = row0 + g * 4;
        __syncthreads();   // protect sH from previous group's readers
        for (int i = tid; i < 4 * IN; i += 256) {
            const int rr = i / IN, c = i % IN;
            const int gr = grp0 + rr;
            sH[rr][c] = (gr < N_NODES) ? H[(long long)gr * IN + c] : 0.f;
        }
        __syncthreads();

        const int grow = grp0 + r;
        if (grow >= N_NODES) continue;
        float accR = 0.f, accT = 0.f;
#pragma unroll
        for (int k = 0; k < IN; ++k) {
            const float h = sH[r][k];          // broadcast, float4-mergeable
            accR += h * sWrel[k * 64 + col];
            accT += h * sWroot[k * 64 + col];
        }
        Yrel[(long long)grow * 64 + col]  = accR;
        Yroot[(long long)grow * 64 + col] = accT;
    }
}

// ---------------------------------------------------------------------------
// CSR build step 1: histogram of dst.
// ---------------------------------------------------------------------------
__global__ __launch_bounds__(256) void hist_dst(const int* __restrict__ dst,
                                                int* __restrict__ cnt) {
    const int e = blockIdx.x * 256 + threadIdx.x;
    if (e < N_EDGES) atomicAdd(&cnt[dst[e]], 1);
}

// ---------------------------------------------------------------------------
// CSR scan, hierarchical. Step A: per-block (256 cnt) sums.
// ---------------------------------------------------------------------------
__global__ __launch_bounds__(256) void scanA_bsum(const int* __restrict__ cnt,
                                                  int* __restrict__ bsum) {
    __shared__ int s[4];
    const int i = blockIdx.x * 256 + threadIdx.x;
    int v = (i < N_NODES) ? cnt[i] : 0;
#pragma unroll
    for (int off = 32; off > 0; off >>= 1) v += __shfl_down(v, off, 64);
    if ((threadIdx.x & 63) == 0) s[threadIdx.x >> 6] = v;
    __syncthreads();
    if (threadIdx.x == 0) bsum[blockIdx.x] = s[0] + s[1] + s[2] + s[3];
}

// ---------------------------------------------------------------------------
// Step B: single block scans NB block-sums -> exclusive block offsets.
// ---------------------------------------------------------------------------
template <int NB>
__global__ __launch_bounds__(256) void scanB_boff(const int* __restrict__ bsum,
                                                  int* __restrict__ boff) {
    __shared__ int s[256];
    const int t = threadIdx.x;
    s[t] = (t < NB) ? bsum[t] : 0;
    __syncthreads();
#pragma unroll
    for (int off = 1; off < 256; off <<= 1) {
        int v = 0;
        if (t >= off) v = s[t - off];
        __syncthreads();
        if (t >= off) s[t] += v;
        __syncthreads();
    }
    if (t < NB) boff[t] = (t == 0) ? 0 : s[t - 1];
}

// ---------------------------------------------------------------------------
// Step C: per-block local exclusive scan + block offset -> rowptr, cursor.
// ---------------------------------------------------------------------------
__global__ __launch_bounds__(256) void scanC_fill(const int* __restrict__ cnt,
                                                  const int* __restrict__ boff,
                                                  int* __restrict__ rowptr,
                                                  int* __restrict__ cursor) {
    __shared__ int s[256];
    const int t = threadIdx.x;
    const int i = blockIdx.x * 256 + t;
    const int v = (i < N_NODES) ? cnt[i] : 0;
    s[t] = v;
    __syncthreads();
#pragma unroll
    for (int off = 1; off < 256; off <<= 1) {
        int u = 0;
        if (t >= off) u = s[t - off];
        __syncthreads();
        if (t >= off) s[t] += u;
        __syncthreads();
    }
    if (i < N_NODES) {
        const int excl = s[t] - v + boff[blockIdx.x];
        rowptr[i] = excl;
        cursor[i] = excl;
    }
    if (i == 0) rowptr[N_NODES] = N_EDGES;
}

// ---------------------------------------------------------------------------
// CSR build step 3: fill column (src) indices.
// ---------------------------------------------------------------------------
__global__ __launch_bounds__(256) void fill_csr(const int* __restrict__ src,
                                                const int* __restrict__ dst,
                                                int* __restrict__ cursor,
                                                int* __restrict__ col) {
    const int e = blockIdx.x * 256 + threadIdx.x;
    if (e >= N_EDGES) return;
    const int p = atomicAdd(&cursor[dst[e]], 1);
    col[p] = src[e];
}

// ---------------------------------------------------------------------------
// Gather aggregation + fused relu(agg + root). One 64-lane wave per node,
// lane = feature. Per edge: one coalesced 256B row read (L2/L3-resident).
// FUSE_POOL: layer 3 — skip Out write, atomically pool graph-0 rows.
// ---------------------------------------------------------------------------
template <bool FUSE_POOL>
__global__ __launch_bounds__(256) void aggregate(const int* __restrict__ rowptr,
                                                 const int* __restrict__ col,
                                                 const float* __restrict__ Y,
                                                 const float* __restrict__ Yroot,
                                                 const int* __restrict__ batch,
                                                 float* __restrict__ Out,
                                                 float* __restrict__ pool) {
    const int node = blockIdx.x * 4 + (threadIdx.x >> 6);
    const int f    = threadIdx.x & 63;
    if (node >= N_NODES) return;
    const int beg = rowptr[node];
    const int end = rowptr[node + 1];
    float acc = 0.f;
    int j = beg;
    for (; j + 1 < end; j += 2) {          // 2-way ILP on the random gathers
        const int s0 = col[j];
        const int s1 = col[j + 1];
        const float v0 = Y[(long long)s0 * 64 + f];
        const float v1 = Y[(long long)s1 * 64 + f];
        acc += v0;
        acc += v1;
    }
    if (j < end) acc += Y[(long long)col[j] * 64 + f];

    float h = fmaxf(acc + Yroot[(long long)node * 64 + f], 0.f);
    if (FUSE_POOL) {
        if (batch[node] == 0) {
            unsafeAtomicAdd(&pool[f], h);
            if (f == 0) unsafeAtomicAdd(&pool[64], 1.0f);
        }
    } else {
        Out[(long long)node * 64 + f] = h;
    }
}

// ---------------------------------------------------------------------------
// Head: means = sums/count; logits = means @ Wfc + bfc; softmax; out[0..9].
// ---------------------------------------------------------------------------
__global__ void head(const float* __restrict__ pool,
                     const float* __restrict__ Wfc,
                     const float* __restrict__ bfc,
                     float* __restrict__ out) {
    __shared__ float logits[TYPE_NUM];
    const int t = threadIdx.x;
    const float inv = 1.0f / fmaxf(pool[64], 1.0f);
    if (t < TYPE_NUM) {
        float acc = bfc[t];
        for (int f = 0; f < HID; ++f)
            acc += pool[f] * inv * Wfc[f * TYPE_NUM + t];
        logits[t] = acc;
    }
    __syncthreads();
    if (t == 0) {
        float m = -1e30f;
        for (int i = 0; i < TYPE_NUM; ++i) m = fmaxf(m, logits[i]);
        float ssum = 0.f;
        float e[TYPE_NUM];
        for (int i = 0; i < TYPE_NUM; ++i) { e[i] = __expf(logits[i] - m); ssum += e[i]; }
        for (int i = 0; i < TYPE_NUM; ++i) out[i] = e[i] / ssum;
    }
}

extern "C" void kernel_launch(void* const* d_in, const int* in_sizes, int n_in,
                              void* d_out, int out_size, void* d_ws, size_t ws_size,
                              hipStream_t stream) {
    const float* x      = (const float*)d_in[0];
    const int*   eidx   = (const int*)d_in[1];
    const int*   batch  = (const int*)d_in[2];
    const float* Wrel1  = (const float*)d_in[3];
    const float* Wroot1 = (const float*)d_in[4];
    const float* Wrel2  = (const float*)d_in[5];
    const float* Wroot2 = (const float*)d_in[6];
    const float* Wrel3  = (const float*)d_in[7];
    const float* Wroot3 = (const float*)d_in[8];
    const float* Wfc    = (const float*)d_in[9];
    const float* bfc    = (const float*)d_in[10];
    float* out = (float*)d_out;

    const int* src = eidx;             // edge_index[0]
    const int* dst = eidx + N_EDGES;   // edge_index[1]

    const long long NN = (long long)N_NODES * HID;        // 3.2M floats
    float* B0   = (float*)d_ws;
    float* B1   = B0 + NN;
    float* B2   = B1 + NN;
    float* pool = B2 + NN;                                // 68 floats (pad)
    int* rowptr = (int*)(pool + 68);                      // N_NODES+1
    int* cursor = rowptr + (N_NODES + 1);                 // N_NODES
    int* cnt    = cursor + N_NODES;                       // N_NODES
    int* bsum   = cnt + N_NODES;                          // 256
    int* boff   = bsum + 256;                             // 256
    int* colidx = boff + 256;                             // N_EDGES

    constexpr int GEMM_ROWS = 32;
    const int gGemm  = (N_NODES + GEMM_ROWS - 1) / GEMM_ROWS;  // 1563
    const int gNode  = (N_NODES + 3) / 4;                      // 12500
    const int gEdge  = (N_EDGES + 255) / 256;                  // 3125
    constexpr int NSCAN = (N_NODES + 255) / 256;               // 196

    // ---- Build CSR (by dst) once; reused by all 3 layers.
    hipMemsetAsync(cnt, 0, N_NODES * sizeof(int), stream);
    hipMemsetAsync(pool, 0, 68 * sizeof(float), stream);
    hist_dst<<<gEdge, 256, 0, stream>>>(dst, cnt);
    scanA_bsum<<<NSCAN, 256, 0, stream>>>(cnt, bsum);
    scanB_boff<NSCAN><<<1, 256, 0, stream>>>(bsum, boff);
    scanC_fill<<<NSCAN, 256, 0, stream>>>(cnt, boff, rowptr, cursor);
    fill_csr<<<gEdge, 256, 0, stream>>>(src, dst, cursor, colidx);

    // ---- Layer 1 (IN=128): x -> Yrel B0, Yroot B1; h1 -> B2
    gemm_dual<FEAT, GEMM_ROWS><<<gGemm, 256, 0, stream>>>(x, Wrel1, Wroot1, B0, B1);
    aggregate<false><<<gNode, 256, 0, stream>>>(rowptr, colidx, B0, B1, batch, B2, pool);

    // ---- Layer 2 (IN=64): h1 B2 -> Yrel B0, Yroot B1; h2 -> B2
    gemm_dual<HID, GEMM_ROWS><<<gGemm, 256, 0, stream>>>(B2, Wrel2, Wroot2, B0, B1);
    aggregate<false><<<gNode, 256, 0, stream>>>(rowptr, colidx, B0, B1, batch, B2, pool);

    // ---- Layer 3 (IN=64): h2 B2 -> Yrel B0, Yroot B1; fused pool (no h3 store)
    gemm_dual<HID, GEMM_ROWS><<<gGemm, 256, 0, stream>>>(B2, Wrel3, Wroot3, B0, B1);
    aggregate<true><<<gNode, 256, 0, stream>>>(rowptr, colidx, B0, B1, batch, nullptr, pool);

    // ---- Head
    head<<<1, 64, 0, stream>>>(pool, Wfc, bfc, out);
}

// Round 4
// 253.410 us; speedup vs baseline: 9.1007x; 1.7605x over previous
//
#include <hip/hip_runtime.h>
#include <hip/hip_bf16.h>

#define N_NODES 50000
#define N_EDGES 800000
#define FEAT 128
#define HID 64
#define TYPE_NUM 10

// ---------------------------------------------------------------------------
// Fused dual GEMM: Yrel = H @ Wrel, Yroot = H @ Wroot. Block = 64 rows x 64
// cols, 256 threads; thread = 4 rows x 4 cols x 2 matrices (32 FMA per k vs
// 2 ds_read_b128 -> FMA-bound). W staged once in LDS as float4; H rows read
// directly from global (L2/L3-resident, 16-lane broadcast per row).
// LIST mode: rows indirected through list[0..*pcount).
// ---------------------------------------------------------------------------
template <int IN, bool LIST>
__global__ __launch_bounds__(256) void gemm_dual(const float* __restrict__ H,
                                                 const float* __restrict__ Wrel,
                                                 const float* __restrict__ Wroot,
                                                 float* __restrict__ Yrel,
                                                 float* __restrict__ Yroot,
                                                 const int* __restrict__ list,
                                                 const int* __restrict__ pcount) {
    __shared__ float4 sWrel[IN * 16];
    __shared__ float4 sWroot[IN * 16];

    const int count = LIST ? *pcount : N_NODES;
    const int li0 = blockIdx.x * 64;
    if (li0 >= count) return;

    const int tid = threadIdx.x;
    const float4* Wr4 = (const float4*)Wrel;
    const float4* Wt4 = (const float4*)Wroot;
    for (int i = tid; i < IN * 16; i += 256) {
        sWrel[i]  = Wr4[i];
        sWroot[i] = Wt4[i];
    }
    __syncthreads();

    const int rg = tid >> 4;   // 0..15 -> 4 rows each
    const int qc = tid & 15;   // 0..15 -> 4 cols each
    const float4* H4 = (const float4*)H;

    int nodeR[4];
    bool valid[4];
    long long hoff[4];
#pragma unroll
    for (int r = 0; r < 4; ++r) {
        const int li = li0 + rg * 4 + r;
        valid[r] = (li < count);
        const int lic = valid[r] ? li : (count - 1);
        nodeR[r] = LIST ? list[lic] : lic;
        hoff[r] = (long long)nodeR[r] * (IN / 4);
    }

    float4 aR[4], aT[4];
#pragma unroll
    for (int r = 0; r < 4; ++r) {
        aR[r] = make_float4(0.f, 0.f, 0.f, 0.f);
        aT[r] = make_float4(0.f, 0.f, 0.f, 0.f);
    }

#pragma unroll 2
    for (int k0 = 0; k0 < IN; k0 += 4) {
        float4 h[4];
#pragma unroll
        for (int r = 0; r < 4; ++r) h[r] = H4[hoff[r] + (k0 >> 2)];
#pragma unroll
        for (int kk = 0; kk < 4; ++kk) {
            const float4 wr = sWrel[(k0 + kk) * 16 + qc];
            const float4 wt = sWroot[(k0 + kk) * 16 + qc];
#pragma unroll
            for (int r = 0; r < 4; ++r) {
                const float hv = (kk == 0) ? h[r].x : (kk == 1) ? h[r].y
                               : (kk == 2) ? h[r].z : h[r].w;
                aR[r].x = fmaf(hv, wr.x, aR[r].x);
                aR[r].y = fmaf(hv, wr.y, aR[r].y);
                aR[r].z = fmaf(hv, wr.z, aR[r].z);
                aR[r].w = fmaf(hv, wr.w, aR[r].w);
                aT[r].x = fmaf(hv, wt.x, aT[r].x);
                aT[r].y = fmaf(hv, wt.y, aT[r].y);
                aT[r].z = fmaf(hv, wt.z, aT[r].z);
                aT[r].w = fmaf(hv, wt.w, aT[r].w);
            }
        }
    }

#pragma unroll
    for (int r = 0; r < 4; ++r) {
        if (!valid[r]) continue;
        ((float4*)Yrel)[(long long)nodeR[r] * 16 + qc]  = aR[r];
        ((float4*)Yroot)[(long long)nodeR[r] * 16 + qc] = aT[r];
    }
}

// ---------------------------------------------------------------------------
// CSR build step 1: histogram of dst.
// ---------------------------------------------------------------------------
__global__ __launch_bounds__(256) void hist_dst(const int* __restrict__ dst,
                                                int* __restrict__ cnt) {
    const int e = blockIdx.x * 256 + threadIdx.x;
    if (e < N_EDGES) atomicAdd(&cnt[dst[e]], 1);
}

// ---------------------------------------------------------------------------
// CSR scan, hierarchical. Step A: per-block (256 cnt) sums.
// ---------------------------------------------------------------------------
__global__ __launch_bounds__(256) void scanA_bsum(const int* __restrict__ cnt,
                                                  int* __restrict__ bsum) {
    __shared__ int s[4];
    const int i = blockIdx.x * 256 + threadIdx.x;
    int v = (i < N_NODES) ? cnt[i] : 0;
#pragma unroll
    for (int off = 32; off > 0; off >>= 1) v += __shfl_down(v, off, 64);
    if ((threadIdx.x & 63) == 0) s[threadIdx.x >> 6] = v;
    __syncthreads();
    if (threadIdx.x == 0) bsum[blockIdx.x] = s[0] + s[1] + s[2] + s[3];
}

// ---------------------------------------------------------------------------
// Step B: single block scans NB block-sums -> exclusive block offsets.
// ---------------------------------------------------------------------------
template <int NB>
__global__ __launch_bounds__(256) void scanB_boff(const int* __restrict__ bsum,
                                                  int* __restrict__ boff) {
    __shared__ int s[256];
    const int t = threadIdx.x;
    s[t] = (t < NB) ? bsum[t] : 0;
    __syncthreads();
#pragma unroll
    for (int off = 1; off < 256; off <<= 1) {
        int v = 0;
        if (t >= off) v = s[t - off];
        __syncthreads();
        if (t >= off) s[t] += v;
        __syncthreads();
    }
    if (t < NB) boff[t] = (t == 0) ? 0 : s[t - 1];
}

// ---------------------------------------------------------------------------
// Step C: per-block local exclusive scan + block offset -> rowptr, cursor.
// ---------------------------------------------------------------------------
__global__ __launch_bounds__(256) void scanC_fill(const int* __restrict__ cnt,
                                                  const int* __restrict__ boff,
                                                  int* __restrict__ rowptr,
                                                  int* __restrict__ cursor) {
    __shared__ int s[256];
    const int t = threadIdx.x;
    const int i = blockIdx.x * 256 + t;
    const int v = (i < N_NODES) ? cnt[i] : 0;
    s[t] = v;
    __syncthreads();
#pragma unroll
    for (int off = 1; off < 256; off <<= 1) {
        int u = 0;
        if (t >= off) u = s[t - off];
        __syncthreads();
        if (t >= off) s[t] += u;
        __syncthreads();
    }
    if (i < N_NODES) {
        const int excl = s[t] - v + boff[blockIdx.x];
        rowptr[i] = excl;
        cursor[i] = excl;
    }
    if (i == 0) rowptr[N_NODES] = N_EDGES;
}

// ---------------------------------------------------------------------------
// CSR build step 3: fill column (src) indices.
// ---------------------------------------------------------------------------
__global__ __launch_bounds__(256) void fill_csr(const int* __restrict__ src,
                                                const int* __restrict__ dst,
                                                int* __restrict__ cursor,
                                                int* __restrict__ col) {
    const int e = blockIdx.x * 256 + threadIdx.x;
    if (e >= N_EDGES) return;
    const int p = atomicAdd(&cursor[dst[e]], 1);
    col[p] = src[e];
}

// ---------------------------------------------------------------------------
// Subset marking: S1 = {batch==0} ∪ {src of edges whose dst has batch==0}.
// ---------------------------------------------------------------------------
__global__ __launch_bounds__(256) void mark_s1(const int* __restrict__ src,
                                               const int* __restrict__ dst,
                                               const int* __restrict__ batch,
                                               int* __restrict__ flag) {
    const int e = blockIdx.x * 256 + threadIdx.x;
    if (e >= N_EDGES) return;
    if (batch[dst[e]] == 0) flag[src[e]] = 1;
}

__global__ __launch_bounds__(256) void compact_lists(const int* __restrict__ flag,
                                                     const int* __restrict__ batch,
                                                     int* __restrict__ list0,
                                                     int* __restrict__ list1,
                                                     int* __restrict__ nctr) {
    const int n = blockIdx.x * 256 + threadIdx.x;
    if (n >= N_NODES) return;
    const bool b0 = (batch[n] == 0);
    if (b0) {
        const int p = atomicAdd(&nctr[0], 1);
        list0[p] = n;
    }
    if (b0 || flag[n]) {
        const int p = atomicAdd(&nctr[1], 1);
        list1[p] = n;
    }
}

// ---------------------------------------------------------------------------
// Gather aggregation + fused relu(agg + root). One 64-lane wave per node,
// lane = feature. LIST mode: nodes indirected through list[0..*pcount).
// FUSE_POOL (with list0 = exactly batch==0): atomically pool, no store.
// ---------------------------------------------------------------------------
template <bool FUSE_POOL, bool LIST>
__global__ __launch_bounds__(256) void aggregate(const int* __restrict__ rowptr,
                                                 const int* __restrict__ col,
                                                 const float* __restrict__ Y,
                                                 const float* __restrict__ Yroot,
                                                 const int* __restrict__ list,
                                                 const int* __restrict__ pcount,
                                                 float* __restrict__ Out,
                                                 float* __restrict__ pool) {
    const int count = LIST ? *pcount : N_NODES;
    const int idx = blockIdx.x * 4 + (threadIdx.x >> 6);
    if (idx >= count) return;
    const int node = LIST ? list[idx] : idx;
    const int f = threadIdx.x & 63;
    const int beg = rowptr[node];
    const int end = rowptr[node + 1];
    float acc = 0.f;
    int j = beg;
    for (; j + 3 < end; j += 4) {      // 4-way MLP on the random gathers
        const int s0 = col[j], s1 = col[j + 1], s2 = col[j + 2], s3 = col[j + 3];
        const float v0 = Y[(long long)s0 * 64 + f];
        const float v1 = Y[(long long)s1 * 64 + f];
        const float v2 = Y[(long long)s2 * 64 + f];
        const float v3 = Y[(long long)s3 * 64 + f];
        acc += v0 + v1 + v2 + v3;
    }
    for (; j < end; ++j) acc += Y[(long long)col[j] * 64 + f];

    const float h = fmaxf(acc + Yroot[(long long)node * 64 + f], 0.f);
    if (FUSE_POOL) {
        unsafeAtomicAdd(&pool[f], h);
    } else {
        Out[(long long)node * 64 + f] = h;
    }
}

// ---------------------------------------------------------------------------
// Head: means = pool/count; logits = means @ Wfc + bfc; softmax; out[0..9].
// ---------------------------------------------------------------------------
__global__ void head(const float* __restrict__ pool,
                     const int* __restrict__ nctr,
                     const float* __restrict__ Wfc,
                     const float* __restrict__ bfc,
                     float* __restrict__ out) {
    __shared__ float logits[TYPE_NUM];
    const int t = threadIdx.x;
    const float inv = 1.0f / fmaxf((float)nctr[0], 1.0f);
    if (t < TYPE_NUM) {
        float acc = bfc[t];
        for (int f = 0; f < HID; ++f)
            acc += pool[f] * inv * Wfc[f * TYPE_NUM + t];
        logits[t] = acc;
    }
    __syncthreads();
    if (t == 0) {
        float m = -1e30f;
        for (int i = 0; i < TYPE_NUM; ++i) m = fmaxf(m, logits[i]);
        float ssum = 0.f;
        float e[TYPE_NUM];
        for (int i = 0; i < TYPE_NUM; ++i) { e[i] = __expf(logits[i] - m); ssum += e[i]; }
        for (int i = 0; i < TYPE_NUM; ++i) out[i] = e[i] / ssum;
    }
}

extern "C" void kernel_launch(void* const* d_in, const int* in_sizes, int n_in,
                              void* d_out, int out_size, void* d_ws, size_t ws_size,
                              hipStream_t stream) {
    const float* x      = (const float*)d_in[0];
    const int*   eidx   = (const int*)d_in[1];
    const int*   batch  = (const int*)d_in[2];
    const float* Wrel1  = (const float*)d_in[3];
    const float* Wroot1 = (const float*)d_in[4];
    const float* Wrel2  = (const float*)d_in[5];
    const float* Wroot2 = (const float*)d_in[6];
    const float* Wrel3  = (const float*)d_in[7];
    const float* Wroot3 = (const float*)d_in[8];
    const float* Wfc    = (const float*)d_in[9];
    const float* bfc    = (const float*)d_in[10];
    float* out = (float*)d_out;

    const int* src = eidx;             // edge_index[0]
    const int* dst = eidx + N_EDGES;   // edge_index[1]

    const long long NN = (long long)N_NODES * HID;        // 3.2M floats
    float* B0   = (float*)d_ws;
    float* B1   = B0 + NN;
    float* B2   = B1 + NN;
    // zero-region (one memset): pool(68f) + nctr(2) + cnt(N) + flag(N)
    float* pool = B2 + NN;
    int* nctr   = (int*)(pool + 68);
    int* cnt    = nctr + 2;
    int* flag   = cnt + N_NODES;
    // non-zeroed scratch
    int* rowptr = flag + N_NODES;                         // N_NODES+1
    int* cursor = rowptr + (N_NODES + 1);
    int* bsum   = cursor + N_NODES;                       // 256
    int* boff   = bsum + 256;                             // 256
    int* list0  = boff + 256;                             // N_NODES
    int* list1  = list0 + N_NODES;                        // N_NODES
    int* colidx = list1 + N_NODES;                        // N_EDGES

    const int gRows  = (N_NODES + 63) / 64;               // 782 (gemm, worst case)
    const int gNode  = (N_NODES + 3) / 4;                 // 12500 (agg, worst case)
    const int gEdge  = (N_EDGES + 255) / 256;             // 3125
    const int gN256  = (N_NODES + 255) / 256;             // 196
    constexpr int NSCAN = (N_NODES + 255) / 256;

    // ---- Zero counters/flags, build CSR + subset lists (reused by all layers)
    hipMemsetAsync(pool, 0, (68 + 2 + 2 * N_NODES) * sizeof(int), stream);
    hist_dst<<<gEdge, 256, 0, stream>>>(dst, cnt);
    scanA_bsum<<<NSCAN, 256, 0, stream>>>(cnt, bsum);
    scanB_boff<NSCAN><<<1, 256, 0, stream>>>(bsum, boff);
    scanC_fill<<<NSCAN, 256, 0, stream>>>(cnt, boff, rowptr, cursor);
    fill_csr<<<gEdge, 256, 0, stream>>>(src, dst, cursor, colidx);
    mark_s1<<<gEdge, 256, 0, stream>>>(src, dst, batch, flag);
    compact_lists<<<gN256, 256, 0, stream>>>(flag, batch, list0, list1, nctr);

    // ---- Layer 1 (IN=128, full): x -> Yrel B0, Yroot B1; h1 -> B2
    gemm_dual<FEAT, false><<<gRows, 256, 0, stream>>>(x, Wrel1, Wroot1, B0, B1, nullptr, nullptr);
    aggregate<false, false><<<gNode, 256, 0, stream>>>(rowptr, colidx, B0, B1, nullptr, nullptr, B2, nullptr);

    // ---- Layer 2 (IN=64): gemm full (Yrel2 needed for all srcs); agg only S1
    gemm_dual<HID, false><<<gRows, 256, 0, stream>>>(B2, Wrel2, Wroot2, B0, B1, nullptr, nullptr);
    aggregate<false, true><<<gNode, 256, 0, stream>>>(rowptr, colidx, B0, B1, list1, nctr + 1, B2, nullptr);

    // ---- Layer 3 (IN=64): gemm only S1 rows; agg+pool only S0 rows
    gemm_dual<HID, true><<<gRows, 256, 0, stream>>>(B2, Wrel3, Wroot3, B0, B1, list1, nctr + 1);
    aggregate<true, true><<<gNode, 256, 0, stream>>>(rowptr, colidx, B0, B1, list0, nctr + 0, nullptr, pool);

    // ---- Head
    head<<<1, 64, 0, stream>>>(pool, nctr, Wfc, bfc, out);
}

// Round 5
// 214.029 us; speedup vs baseline: 10.7752x; 1.1840x over previous
//
#include <hip/hip_runtime.h>
#include <hip/hip_bf16.h>

#define N_NODES 50000
#define N_EDGES 800000
#define FEAT 128
#define HID 64
#define TYPE_NUM 10

// ---------------------------------------------------------------------------
// Fused dual GEMM: Yrel = H @ Wrel, Yroot = H @ Wroot. Block = 64 rows x 64
// cols, 256 threads; thread = 4 rows x 4 cols x 2 matrices (32 FMA per k vs
// 2 ds_read_b128 -> FMA-bound). W staged once in LDS as float4; H rows read
// directly from global (L2/L3-resident, 16-lane broadcast per row).
// LIST mode: rows indirected through list[0..*pcount).
// ---------------------------------------------------------------------------
template <int IN, bool LIST>
__global__ __launch_bounds__(256) void gemm_dual(const float* __restrict__ H,
                                                 const float* __restrict__ Wrel,
                                                 const float* __restrict__ Wroot,
                                                 float* __restrict__ Yrel,
                                                 float* __restrict__ Yroot,
                                                 const int* __restrict__ list,
                                                 const int* __restrict__ pcount) {
    __shared__ float4 sWrel[IN * 16];
    __shared__ float4 sWroot[IN * 16];

    const int count = LIST ? *pcount : N_NODES;
    const int li0 = blockIdx.x * 64;
    if (li0 >= count) return;

    const int tid = threadIdx.x;
    const float4* Wr4 = (const float4*)Wrel;
    const float4* Wt4 = (const float4*)Wroot;
    for (int i = tid; i < IN * 16; i += 256) {
        sWrel[i]  = Wr4[i];
        sWroot[i] = Wt4[i];
    }
    __syncthreads();

    const int rg = tid >> 4;   // 0..15 -> 4 rows each
    const int qc = tid & 15;   // 0..15 -> 4 cols each
    const float4* H4 = (const float4*)H;

    int nodeR[4];
    bool valid[4];
    long long hoff[4];
#pragma unroll
    for (int r = 0; r < 4; ++r) {
        const int li = li0 + rg * 4 + r;
        valid[r] = (li < count);
        const int lic = valid[r] ? li : (count - 1);
        nodeR[r] = LIST ? list[lic] : lic;
        hoff[r] = (long long)nodeR[r] * (IN / 4);
    }

    float4 aR[4], aT[4];
#pragma unroll
    for (int r = 0; r < 4; ++r) {
        aR[r] = make_float4(0.f, 0.f, 0.f, 0.f);
        aT[r] = make_float4(0.f, 0.f, 0.f, 0.f);
    }

#pragma unroll 2
    for (int k0 = 0; k0 < IN; k0 += 4) {
        float4 h[4];
#pragma unroll
        for (int r = 0; r < 4; ++r) h[r] = H4[hoff[r] + (k0 >> 2)];
#pragma unroll
        for (int kk = 0; kk < 4; ++kk) {
            const float4 wr = sWrel[(k0 + kk) * 16 + qc];
            const float4 wt = sWroot[(k0 + kk) * 16 + qc];
#pragma unroll
            for (int r = 0; r < 4; ++r) {
                const float hv = (kk == 0) ? h[r].x : (kk == 1) ? h[r].y
                               : (kk == 2) ? h[r].z : h[r].w;
                aR[r].x = fmaf(hv, wr.x, aR[r].x);
                aR[r].y = fmaf(hv, wr.y, aR[r].y);
                aR[r].z = fmaf(hv, wr.z, aR[r].z);
                aR[r].w = fmaf(hv, wr.w, aR[r].w);
                aT[r].x = fmaf(hv, wt.x, aT[r].x);
                aT[r].y = fmaf(hv, wt.y, aT[r].y);
                aT[r].z = fmaf(hv, wt.z, aT[r].z);
                aT[r].w = fmaf(hv, wt.w, aT[r].w);
            }
        }
    }

#pragma unroll
    for (int r = 0; r < 4; ++r) {
        if (!valid[r]) continue;
        ((float4*)Yrel)[(long long)nodeR[r] * 16 + qc]  = aR[r];
        ((float4*)Yroot)[(long long)nodeR[r] * 16 + qc] = aT[r];
    }
}

// ---------------------------------------------------------------------------
// Edge pass 1 (fused): per-dst histogram WITH rank capture (coalesced write),
// plus S1 marking (src of edges into graph-0 dsts).
// ---------------------------------------------------------------------------
__global__ __launch_bounds__(256) void hist_mark(const int* __restrict__ src,
                                                 const int* __restrict__ dst,
                                                 const int* __restrict__ batch,
                                                 int* __restrict__ cnt,
                                                 int* __restrict__ rank,
                                                 int* __restrict__ flag) {
    const int e = blockIdx.x * 256 + threadIdx.x;
    if (e >= N_EDGES) return;
    const int d = dst[e];
    rank[e] = atomicAdd(&cnt[d], 1);
    if (batch[d] == 0) flag[src[e]] = 1;
}

// ---------------------------------------------------------------------------
// CSR scan, hierarchical. Step A: per-block (256 cnt) sums.
// ---------------------------------------------------------------------------
__global__ __launch_bounds__(256) void scanA_bsum(const int* __restrict__ cnt,
                                                  int* __restrict__ bsum) {
    __shared__ int s[4];
    const int i = blockIdx.x * 256 + threadIdx.x;
    int v = (i < N_NODES) ? cnt[i] : 0;
#pragma unroll
    for (int off = 32; off > 0; off >>= 1) v += __shfl_down(v, off, 64);
    if ((threadIdx.x & 63) == 0) s[threadIdx.x >> 6] = v;
    __syncthreads();
    if (threadIdx.x == 0) bsum[blockIdx.x] = s[0] + s[1] + s[2] + s[3];
}

// ---------------------------------------------------------------------------
// Step B: single block scans NB block-sums -> exclusive block offsets.
// ---------------------------------------------------------------------------
template <int NB>
__global__ __launch_bounds__(256) void scanB_boff(const int* __restrict__ bsum,
                                                  int* __restrict__ boff) {
    __shared__ int s[256];
    const int t = threadIdx.x;
    s[t] = (t < NB) ? bsum[t] : 0;
    __syncthreads();
#pragma unroll
    for (int off = 1; off < 256; off <<= 1) {
        int v = 0;
        if (t >= off) v = s[t - off];
        __syncthreads();
        if (t >= off) s[t] += v;
        __syncthreads();
    }
    if (t < NB) boff[t] = (t == 0) ? 0 : s[t - 1];
}

// ---------------------------------------------------------------------------
// Step C (fused): per-block local exclusive scan + block offset -> rowptr,
// plus S0/S1 list compaction (order nondeterminism only perturbs f32
// pool-atomic rounding, far below threshold).
// ---------------------------------------------------------------------------
__global__ __launch_bounds__(256) void scanC_compact(const int* __restrict__ cnt,
                                                     const int* __restrict__ boff,
                                                     const int* __restrict__ batch,
                                                     const int* __restrict__ flag,
                                                     int* __restrict__ rowptr,
                                                     int* __restrict__ list0,
                                                     int* __restrict__ list1,
                                                     int* __restrict__ nctr) {
    __shared__ int s[256];
    const int t = threadIdx.x;
    const int i = blockIdx.x * 256 + t;
    const int v = (i < N_NODES) ? cnt[i] : 0;
    s[t] = v;
    __syncthreads();
#pragma unroll
    for (int off = 1; off < 256; off <<= 1) {
        int u = 0;
        if (t >= off) u = s[t - off];
        __syncthreads();
        if (t >= off) s[t] += u;
        __syncthreads();
    }
    if (i < N_NODES) {
        rowptr[i] = s[t] - v + boff[blockIdx.x];
        const bool b0 = (batch[i] == 0);
        if (b0) {
            const int p = atomicAdd(&nctr[0], 1);
            list0[p] = i;
        }
        if (b0 || flag[i]) {
            const int p = atomicAdd(&nctr[1], 1);
            list1[p] = i;
        }
    }
    if (i == 0) rowptr[N_NODES] = N_EDGES;
}

// ---------------------------------------------------------------------------
// Edge pass 2: atomic-FREE CSR fill. col[rowptr[dst]+rank] = src.
// 2 edges/thread via int2 for latency ILP.
// ---------------------------------------------------------------------------
__global__ __launch_bounds__(256) void fill_csr2(const int* __restrict__ src,
                                                 const int* __restrict__ dst,
                                                 const int* __restrict__ rank,
                                                 const int* __restrict__ rowptr,
                                                 int* __restrict__ col) {
    const int e0 = (blockIdx.x * 256 + threadIdx.x) * 2;
    if (e0 >= N_EDGES) return;
    const int2 s2 = *reinterpret_cast<const int2*>(src + e0);
    const int2 d2 = *reinterpret_cast<const int2*>(dst + e0);
    const int2 r2 = *reinterpret_cast<const int2*>(rank + e0);
    const int p0 = rowptr[d2.x] + r2.x;
    const int p1 = rowptr[d2.y] + r2.y;
    col[p0] = s2.x;
    col[p1] = s2.y;
}

// ---------------------------------------------------------------------------
// Gather aggregation + fused relu(agg + root). One 64-lane wave per node,
// lane = feature. LIST mode: nodes indirected through list[0..*pcount).
// FUSE_POOL (with list0 = exactly batch==0): atomically pool, no store.
// ---------------------------------------------------------------------------
template <bool FUSE_POOL, bool LIST>
__global__ __launch_bounds__(256) void aggregate(const int* __restrict__ rowptr,
                                                 const int* __restrict__ col,
                                                 const float* __restrict__ Y,
                                                 const float* __restrict__ Yroot,
                                                 const int* __restrict__ list,
                                                 const int* __restrict__ pcount,
                                                 float* __restrict__ Out,
                                                 float* __restrict__ pool) {
    const int count = LIST ? *pcount : N_NODES;
    const int idx = blockIdx.x * 4 + (threadIdx.x >> 6);
    if (idx >= count) return;
    const int node = LIST ? list[idx] : idx;
    const int f = threadIdx.x & 63;
    const int beg = rowptr[node];
    const int end = rowptr[node + 1];
    float acc = 0.f;
    int j = beg;
    for (; j + 3 < end; j += 4) {      // 4-way MLP on the random gathers
        const int s0 = col[j], s1 = col[j + 1], s2 = col[j + 2], s3 = col[j + 3];
        const float v0 = Y[(long long)s0 * 64 + f];
        const float v1 = Y[(long long)s1 * 64 + f];
        const float v2 = Y[(long long)s2 * 64 + f];
        const float v3 = Y[(long long)s3 * 64 + f];
        acc += v0 + v1 + v2 + v3;
    }
    for (; j < end; ++j) acc += Y[(long long)col[j] * 64 + f];

    const float h = fmaxf(acc + Yroot[(long long)node * 64 + f], 0.f);
    if (FUSE_POOL) {
        unsafeAtomicAdd(&pool[f], h);
    } else {
        Out[(long long)node * 64 + f] = h;
    }
}

// ---------------------------------------------------------------------------
// Head: means = pool/count; logits = means @ Wfc + bfc; softmax; out[0..9].
// ---------------------------------------------------------------------------
__global__ void head(const float* __restrict__ pool,
                     const int* __restrict__ nctr,
                     const float* __restrict__ Wfc,
                     const float* __restrict__ bfc,
                     float* __restrict__ out) {
    __shared__ float logits[TYPE_NUM];
    const int t = threadIdx.x;
    const float inv = 1.0f / fmaxf((float)nctr[0], 1.0f);
    if (t < TYPE_NUM) {
        float acc = bfc[t];
        for (int f = 0; f < HID; ++f)
            acc += pool[f] * inv * Wfc[f * TYPE_NUM + t];
        logits[t] = acc;
    }
    __syncthreads();
    if (t == 0) {
        float m = -1e30f;
        for (int i = 0; i < TYPE_NUM; ++i) m = fmaxf(m, logits[i]);
        float ssum = 0.f;
        float e[TYPE_NUM];
        for (int i = 0; i < TYPE_NUM; ++i) { e[i] = __expf(logits[i] - m); ssum += e[i]; }
        for (int i = 0; i < TYPE_NUM; ++i) out[i] = e[i] / ssum;
    }
}

extern "C" void kernel_launch(void* const* d_in, const int* in_sizes, int n_in,
                              void* d_out, int out_size, void* d_ws, size_t ws_size,
                              hipStream_t stream) {
    const float* x      = (const float*)d_in[0];
    const int*   eidx   = (const int*)d_in[1];
    const int*   batch  = (const int*)d_in[2];
    const float* Wrel1  = (const float*)d_in[3];
    const float* Wroot1 = (const float*)d_in[4];
    const float* Wrel2  = (const float*)d_in[5];
    const float* Wroot2 = (const float*)d_in[6];
    const float* Wrel3  = (const float*)d_in[7];
    const float* Wroot3 = (const float*)d_in[8];
    const float* Wfc    = (const float*)d_in[9];
    const float* bfc    = (const float*)d_in[10];
    float* out = (float*)d_out;

    const int* src = eidx;             // edge_index[0]
    const int* dst = eidx + N_EDGES;   // edge_index[1]

    const long long NN = (long long)N_NODES * HID;        // 3.2M floats
    float* B0   = (float*)d_ws;
    float* B1   = B0 + NN;
    float* B2   = B1 + NN;
    // zero-region (one memset): pool(68f) + nctr(2) + cnt(N) + flag(N)
    float* pool = B2 + NN;
    int* nctr   = (int*)(pool + 68);
    int* cnt    = nctr + 2;
    int* flag   = cnt + N_NODES;
    // non-zeroed scratch
    int* rowptr = flag + N_NODES;                         // N_NODES+1
    int* bsum   = rowptr + (N_NODES + 1);                 // 256
    int* boff   = bsum + 256;                             // 256
    int* list0  = boff + 256;                             // N_NODES
    int* list1  = list0 + N_NODES;                        // N_NODES
    int* rank   = list1 + N_NODES;                        // N_EDGES
    int* colidx = rank + N_EDGES;                         // N_EDGES

    const int gRows  = (N_NODES + 63) / 64;               // 782 (gemm, worst case)
    const int gNode  = (N_NODES + 3) / 4;                 // 12500 (agg, worst case)
    const int gEdge  = (N_EDGES + 255) / 256;             // 3125
    const int gEdge2 = (N_EDGES / 2 + 255) / 256;         // 1563
    constexpr int NSCAN = (N_NODES + 255) / 256;          // 196

    // ---- Zero counters/flags; build CSR + subset lists (5 kernels).
    hipMemsetAsync(pool, 0, (68 + 2 + 2 * N_NODES) * sizeof(int), stream);
    hist_mark<<<gEdge, 256, 0, stream>>>(src, dst, batch, cnt, rank, flag);
    scanA_bsum<<<NSCAN, 256, 0, stream>>>(cnt, bsum);
    scanB_boff<NSCAN><<<1, 256, 0, stream>>>(bsum, boff);
    scanC_compact<<<NSCAN, 256, 0, stream>>>(cnt, boff, batch, flag, rowptr, list0, list1, nctr);
    fill_csr2<<<gEdge2, 256, 0, stream>>>(src, dst, rank, rowptr, colidx);

    // ---- Layer 1 (IN=128, full): x -> Yrel B0, Yroot B1; h1 -> B2
    gemm_dual<FEAT, false><<<gRows, 256, 0, stream>>>(x, Wrel1, Wroot1, B0, B1, nullptr, nullptr);
    aggregate<false, false><<<gNode, 256, 0, stream>>>(rowptr, colidx, B0, B1, nullptr, nullptr, B2, nullptr);

    // ---- Layer 2 (IN=64): gemm full (Yrel2 needed for all srcs); agg only S1
    gemm_dual<HID, false><<<gRows, 256, 0, stream>>>(B2, Wrel2, Wroot2, B0, B1, nullptr, nullptr);
    aggregate<false, true><<<gNode, 256, 0, stream>>>(rowptr, colidx, B0, B1, list1, nctr + 1, B2, nullptr);

    // ---- Layer 3 (IN=64): gemm only S1 rows; agg+pool only S0 rows
    gemm_dual<HID, true><<<gRows, 256, 0, stream>>>(B2, Wrel3, Wroot3, B0, B1, list1, nctr + 1);
    aggregate<true, true><<<gNode, 256, 0, stream>>>(rowptr, colidx, B0, B1, list0, nctr + 0, nullptr, pool);

    // ---- Head
    head<<<1, 64, 0, stream>>>(pool, nctr, Wfc, bfc, out);
}